// Round 1
// baseline (1616.513 us; speedup 1.0000x reference)
//
#include <hip/hip_runtime.h>
#include <hip/hip_bf16.h>
#include <hip/hip_fp16.h>
#include <stdint.h>

// Problem: T=512, B=128, INPUT=256, HIDDEN=512
//   xp = einsum('tbi,hi->tbh', x, Wx) + b      (phase 1, parallel GEMM)
//   h_{t+1} = tanh(xp_t + h_t @ Wh^T)          (phase 2, 512 sequential steps)
//   out = [h0(=0); h1..h512]  fp32, shape (513,128,512)
//
// R6: scan rework. Previous scan was 2.9 us/step: ~1.16 us L2 weight
// re-streaming (rows 3..7 re-fetched every step), ~0.37 us un-hidden HBM
// latency on the xp read, 8-way LDS bank conflict on h chunk reads.
//  (a) ALL 8 weight rows now VGPR-resident: 64 uint4 = 256 VGPRs/thread,
//      fits at 2 waves/SIMD (__launch_bounds__(512,2), budget 1024).
//  (b) xp_{t+1} prefetched at top of step t (latency hidden under dots).
//  (c) h chunks stored at stride 72 halves (144 B) -> banks rotate 4/chunk,
//      8-way conflict eliminated; same-address lanes broadcast free.
#define T_STEPS 512
#define BATCH   128
#define NIN     256
#define HID     512

typedef _Float16 f16x2 __attribute__((ext_vector_type(2)));

__device__ __forceinline__ float fdot2u(uint32_t a, uint32_t b, float c) {
#if __has_builtin(__builtin_amdgcn_fdot2)
  return __builtin_amdgcn_fdot2(__builtin_bit_cast(f16x2, a),
                                __builtin_bit_cast(f16x2, b), c, false);
#else
  __half2 ha = __builtin_bit_cast(__half2, a);
  __half2 hb = __builtin_bit_cast(__half2, b);
  return c + __half2float(ha.x) * __half2float(hb.x)
           + __half2float(ha.y) * __half2float(hb.y);
#endif
}

// 16 halves (uint4 pair) dot 16 halves, fp32 accumulate
__device__ __forceinline__ float dot8(uint4 w, uint4 x, float a) {
  a = fdot2u(w.x, x.x, a);
  a = fdot2u(w.y, x.y, a);
  a = fdot2u(w.z, x.z, a);
  a = fdot2u(w.w, x.w, a);
  return a;
}

// 64 f16 weights (8 uint4) dotted with 64 f16 h values, fp32 accumulate.
__device__ __forceinline__ float dot_row(const uint4* w, const uint4* h) {
  float a = 0.f;
#pragma unroll
  for (int i = 0; i < 8; ++i) a = dot8(w[i], h[i], a);
  return a;
}

// ------------- phase 0: split + convert W (fp32[512][768]) to f16 -----------
__global__ void prep_w(const float* __restrict__ W,
                       __half* __restrict__ Wx, __half* __restrict__ Wh) {
  int idx = blockIdx.x * 256 + threadIdx.x;   // exactly 512*768 threads
  int h = idx / (NIN + HID);
  int c = idx - h * (NIN + HID);
  float v = W[idx];
  if (c < NIN) Wx[h * NIN + c] = __float2half(v);
  else         Wh[h * HID + (c - NIN)] = __float2half(v);
}

// ---------------- phase 1: xp[m][n] = sum_k x[m][k]*Wx[n][k] + b[n] ----------
// Grid 4096 = 2048 m-blocks x 2 n-blocks. Block tile: 32 rows x 256 cols.
// 256 threads; thread = 8 rows x 4 cols. x tile staged in LDS as f16
// (broadcast reads), Wx streamed from L2. v_dot2_f32_f16, fp32 accumulate.
// Output fp32 straight into d_out blocks 1..512.
__launch_bounds__(256)
__global__ void gemm_xp(const float* __restrict__ x,
                        const __half* __restrict__ Wx,
                        const float* __restrict__ bias,
                        float* __restrict__ xp) {
  __shared__ __align__(16) __half xs[32][256];

  const int bid = blockIdx.x;
  const int m0 = (bid >> 1) * 32;
  const int n0 = (bid & 1) * 256;
  const int tid = threadIdx.x;

  // stage x[m0..m0+31][0..255] (fp32) -> f16 LDS
  {
    int r = tid >> 3, cb = (tid & 7) * 32;
    const float* src = x + (size_t)(m0 + r) * NIN + cb;
    union { __half h[8]; uint4 u; } cv;
#pragma unroll
    for (int i = 0; i < 4; ++i) {
      float4 f0 = *(const float4*)(src + i * 8);
      float4 f1 = *(const float4*)(src + i * 8 + 4);
      cv.h[0] = __float2half(f0.x); cv.h[1] = __float2half(f0.y);
      cv.h[2] = __float2half(f0.z); cv.h[3] = __float2half(f0.w);
      cv.h[4] = __float2half(f1.x); cv.h[5] = __float2half(f1.y);
      cv.h[6] = __float2half(f1.z); cv.h[7] = __float2half(f1.w);
      *(uint4*)(void*)&xs[r][cb + i * 8] = cv.u;
    }
  }
  __syncthreads();

  const int rg = tid >> 6;          // row group: rows rg*8 .. rg*8+7
  const int c0 = tid & 63;          // cols n0 + c0 + 64j, j<4

  float acc[8][4];
#pragma unroll
  for (int r = 0; r < 8; ++r)
#pragma unroll
    for (int j = 0; j < 4; ++j) acc[r][j] = 0.f;

  for (int kc = 0; kc < NIN; kc += 32) {
    uint4 w[4][4];
#pragma unroll
    for (int j = 0; j < 4; ++j) {
      const __half* wp = Wx + (size_t)(n0 + c0 + 64 * j) * NIN + kc;
#pragma unroll
      for (int i = 0; i < 4; ++i) w[j][i] = *(const uint4*)(wp + i * 8);
    }
#pragma unroll
    for (int r = 0; r < 8; ++r) {
      uint4 xv[4];
#pragma unroll
      for (int i = 0; i < 4; ++i)
        xv[i] = *(const uint4*)(const void*)&xs[rg * 8 + r][kc + i * 8];
#pragma unroll
      for (int j = 0; j < 4; ++j)
#pragma unroll
        for (int i = 0; i < 4; ++i) acc[r][j] = dot8(w[j][i], xv[i], acc[r][j]);
    }
  }

  float bj[4];
#pragma unroll
  for (int j = 0; j < 4; ++j) bj[j] = bias[n0 + c0 + 64 * j];
#pragma unroll
  for (int r = 0; r < 8; ++r) {
    float* dst = xp + (size_t)(m0 + rg * 8 + r) * HID + n0 + c0;
#pragma unroll
    for (int j = 0; j < 4; ++j) dst[64 * j] = acc[r][j] + bj[j];
  }
}

// ---------------- phase 2: sequential scan, one WG (512 thr) per batch -------
// Thread (rb = tid>>3, ks = tid&7) owns rows rb*8..rb*8+7, k in [ks*64,+64).
// ALL 8 weight rows VGPR-resident (256 VGPRs). h staged in LDS with 72-half
// chunk stride (bank-rotated). xp_{t+1} prefetched during step t's dots.
// fp32 accumulate; cross-ks reduction through LDS (stride 513).
// Block t+1 of io holds xp_t (fp32); thread tid reads it then overwrites the
// SAME element with h_{t+1} (fp32) — in-place safe, read-before-write.
#define HCH 72   // padded h chunk stride (halves): 144 B -> bank rot 4/chunk
__launch_bounds__(512, 2)
__global__ void rnn_scan(const __half* __restrict__ Wh, float* io) {
  __shared__ __align__(16) __half hsh[8 * HCH];
  __shared__ float part[8 * 513];

  const int b   = blockIdx.x;
  const int tid = threadIdx.x;
  const int ks  = tid & 7;
  const int R0  = (tid >> 3) * 8;
  const __half* wbase = Wh + (size_t)R0 * HID + ks * 64;

  // all 8 rows resident: 64 uint4 = 256 VGPRs/thread
  uint4 wres[8][8];
#pragma unroll
  for (int r = 0; r < 8; ++r)
#pragma unroll
    for (int i = 0; i < 8; ++i)
      wres[r][i] = *(const uint4*)(wbase + (size_t)r * HID + i * 8);

  // h0 = 0 ; emit output block t=0
  const int hwb = (tid >> 6) * HCH + (tid & 63);  // my h slot (padded layout)
  hsh[hwb] = __float2half(0.f);
  io[(size_t)b * HID + tid] = 0.f;
  __syncthreads();

  const uint4* hv = (const uint4*)(const void*)(hsh + ks * HCH);
  float* iorow = io + (size_t)BATCH * HID + (size_t)b * HID + tid;
  float* pwr = part + ks * 513 + R0;

  float xpv = *iorow;                    // xp_0

  for (int t = 0; t < T_STEPS; ++t) {
    // prefetch next step's xp — ~1000 cycles of dots below hide the latency
    float xpn = 0.f;
    if (t + 1 < T_STEPS) xpn = iorow[BATCH * HID];

    uint4 hj[8];
#pragma unroll
    for (int i = 0; i < 8; ++i) hj[i] = hv[i];

    float acc[8];
#pragma unroll
    for (int r = 0; r < 8; ++r) acc[r] = dot_row(wres[r], hj);

#pragma unroll
    for (int r = 0; r < 8; ++r) pwr[r] = acc[r];
    __syncthreads();

    // thread tid == row n: reduce 8 k-slices, add xp, tanh, emit
    float s = 0.f;
#pragma unroll
    for (int k = 0; k < 8; ++k) s += part[k * 513 + tid];
    s += xpv;                            // xp_t (prefetched)
    float e  = __expf(fminf(fmaxf(2.f * s, -40.f), 40.f));
    float hn = (e - 1.f) / (e + 1.f);
    *iorow = hn;                         // h_{t+1} overwrites xp_t in place
    hsh[hwb] = __float2half(hn);
    __syncthreads();

    xpv = xpn;
    iorow += BATCH * HID;
  }
}

extern "C" void kernel_launch(void* const* d_in, const int* in_sizes, int n_in,
                              void* d_out, int out_size, void* d_ws, size_t ws_size,
                              hipStream_t stream) {
  const float* x    = (const float*)d_in[0];   // (512,128,256) fp32
  const float* W    = (const float*)d_in[1];   // (512,768) fp32
  const float* bias = (const float*)d_in[2];   // (512,) fp32

  // d_ws: 768 KiB for f16 weight copies (proven available in R4)
  char* ws = (char*)d_ws;
  __half* Wx = (__half*)ws;                    // 512*256*2 = 256 KiB
  __half* Wh = (__half*)(ws + 262144);         // 512*512*2 = 512 KiB

  // xp lives in d_out blocks 1..512 (fp32), overwritten in place by the scan
  float* io = (float*)d_out;
  float* xp = io + (size_t)BATCH * HID;

  prep_w<<<1536, 256, 0, stream>>>(W, Wx, Wh);
  gemm_xp<<<4096, 256, 0, stream>>>(x, Wx, bias, xp);
  rnn_scan<<<BATCH, 512, 0, stream>>>(Wh, io);
}

// Round 2
// 1155.550 us; speedup vs baseline: 1.3989x; 1.3989x over previous
//
#include <hip/hip_runtime.h>
#include <hip/hip_bf16.h>
#include <hip/hip_fp16.h>
#include <stdint.h>

// Problem: T=512, B=128, INPUT=256, HIDDEN=512
//   xp = einsum('tbi,hi->tbh', x, Wx) + b      (phase 1, parallel GEMM)
//   h_{t+1} = tanh(xp_t + h_t @ Wh^T)          (phase 2, 512 sequential steps)
//   out = [h0(=0); h1..h512]  fp32, shape (513,128,512)
//
// R7: R6's "residency" never happened (VGPR_Count=128 -> compiler
// rematerialized the weight loads; scan stayed L2-BW-bound at ~26 TB/s).
// Now: 6 of 8 rows VGPR-resident (192 regs, asm-pinned so remat is
// impossible), rows 6..7 staged ONCE into LDS (128 KB) and re-read each
// step. LDS chunks XOR-swizzled (slot = i^ks) so the 8 ks-slices hit all
// 32 banks; without it all 64 lanes hit one 4-bank column (64-way).
// Per-step: 256 fdot2 (VALU ~1168 cyc/SIMD) overlapped with 16
// ds_read_b128/thread (LDS pipe ~1024 cyc/CU). Weight L2 traffic: zero.
#define T_STEPS 512
#define BATCH   128
#define NIN     256
#define HID     512

typedef _Float16 f16x2 __attribute__((ext_vector_type(2)));
typedef unsigned int u32x4 __attribute__((ext_vector_type(4)));

__device__ __forceinline__ float fdot2u(uint32_t a, uint32_t b, float c) {
#if __has_builtin(__builtin_amdgcn_fdot2)
  return __builtin_amdgcn_fdot2(__builtin_bit_cast(f16x2, a),
                                __builtin_bit_cast(f16x2, b), c, false);
#else
  __half2 ha = __builtin_bit_cast(__half2, a);
  __half2 hb = __builtin_bit_cast(__half2, b);
  return c + __half2float(ha.x) * __half2float(hb.x)
           + __half2float(ha.y) * __half2float(hb.y);
#endif
}

__device__ __forceinline__ float dot8v(u32x4 w, u32x4 x, float a) {
  a = fdot2u(w.x, x.x, a);
  a = fdot2u(w.y, x.y, a);
  a = fdot2u(w.z, x.z, a);
  a = fdot2u(w.w, x.w, a);
  return a;
}

// HIP uint4 variant for gemm_xp (unchanged)
__device__ __forceinline__ float dot8(uint4 w, uint4 x, float a) {
  a = fdot2u(w.x, x.x, a);
  a = fdot2u(w.y, x.y, a);
  a = fdot2u(w.z, x.z, a);
  a = fdot2u(w.w, x.w, a);
  return a;
}

// ------------- phase 0: split + convert W (fp32[512][768]) to f16 -----------
__global__ void prep_w(const float* __restrict__ W,
                       __half* __restrict__ Wx, __half* __restrict__ Wh) {
  int idx = blockIdx.x * 256 + threadIdx.x;   // exactly 512*768 threads
  int h = idx / (NIN + HID);
  int c = idx - h * (NIN + HID);
  float v = W[idx];
  if (c < NIN) Wx[h * NIN + c] = __float2half(v);
  else         Wh[h * HID + (c - NIN)] = __float2half(v);
}

// ---------------- phase 1: xp[m][n] = sum_k x[m][k]*Wx[n][k] + b[n] ----------
__launch_bounds__(256)
__global__ void gemm_xp(const float* __restrict__ x,
                        const __half* __restrict__ Wx,
                        const float* __restrict__ bias,
                        float* __restrict__ xp) {
  __shared__ __align__(16) __half xs[32][256];

  const int bid = blockIdx.x;
  const int m0 = (bid >> 1) * 32;
  const int n0 = (bid & 1) * 256;
  const int tid = threadIdx.x;

  {
    int r = tid >> 3, cb = (tid & 7) * 32;
    const float* src = x + (size_t)(m0 + r) * NIN + cb;
    union { __half h[8]; uint4 u; } cv;
#pragma unroll
    for (int i = 0; i < 4; ++i) {
      float4 f0 = *(const float4*)(src + i * 8);
      float4 f1 = *(const float4*)(src + i * 8 + 4);
      cv.h[0] = __float2half(f0.x); cv.h[1] = __float2half(f0.y);
      cv.h[2] = __float2half(f0.z); cv.h[3] = __float2half(f0.w);
      cv.h[4] = __float2half(f1.x); cv.h[5] = __float2half(f1.y);
      cv.h[6] = __float2half(f1.z); cv.h[7] = __float2half(f1.w);
      *(uint4*)(void*)&xs[r][cb + i * 8] = cv.u;
    }
  }
  __syncthreads();

  const int rg = tid >> 6;
  const int c0 = tid & 63;

  float acc[8][4];
#pragma unroll
  for (int r = 0; r < 8; ++r)
#pragma unroll
    for (int j = 0; j < 4; ++j) acc[r][j] = 0.f;

  for (int kc = 0; kc < NIN; kc += 32) {
    uint4 w[4][4];
#pragma unroll
    for (int j = 0; j < 4; ++j) {
      const __half* wp = Wx + (size_t)(n0 + c0 + 64 * j) * NIN + kc;
#pragma unroll
      for (int i = 0; i < 4; ++i) w[j][i] = *(const uint4*)(wp + i * 8);
    }
#pragma unroll
    for (int r = 0; r < 8; ++r) {
      uint4 xv[4];
#pragma unroll
      for (int i = 0; i < 4; ++i)
        xv[i] = *(const uint4*)(const void*)&xs[rg * 8 + r][kc + i * 8];
#pragma unroll
      for (int j = 0; j < 4; ++j)
#pragma unroll
        for (int i = 0; i < 4; ++i) acc[r][j] = dot8(w[j][i], xv[i], acc[r][j]);
    }
  }

  float bj[4];
#pragma unroll
  for (int j = 0; j < 4; ++j) bj[j] = bias[n0 + c0 + 64 * j];
#pragma unroll
  for (int r = 0; r < 8; ++r) {
    float* dst = xp + (size_t)(m0 + rg * 8 + r) * HID + n0 + c0;
#pragma unroll
    for (int j = 0; j < 4; ++j) dst[64 * j] = acc[r][j] + bj[j];
  }
}

// ---------------- phase 2: sequential scan, one WG (512 thr) per batch -------
// Thread (rb = tid>>3, ks = tid&7) owns rows rb*8..rb*8+7, k in [ks*64,+64).
// Rows 0..5 VGPR-resident (48 u32x4 = 192 regs, asm-pinned). Rows 6..7 in
// LDS (128 KB, staged once, XOR-swizzled slot=i^ks). h in LDS at 72-half
// chunk stride. xp_{t+1} prefetched. Cross-ks reduce via LDS (stride 520,
// float4 writes). io block t+1 holds xp_t, overwritten in place by h_{t+1}.
#define HCH 72   // h chunk stride in halves (144 B -> bank rot 4/chunk)
#define PST 520  // part row stride in floats (2080 B, 16B-aligned)
__launch_bounds__(512, 2)
__global__ void rnn_scan(const __half* __restrict__ Wh, float* io) {
  __shared__ __align__(16) char  whl[131072];       // rows 6,7 of each rb
  __shared__ __align__(16) float part[8 * PST];     // 16640 B
  __shared__ __align__(16) __half hsh[8 * HCH];     // 1152 B   (tot 145.4 KiB)

  const int b   = blockIdx.x;
  const int tid = threadIdx.x;
  const int ks  = tid & 7;
  const int rb  = tid >> 3;
  const int R0  = rb * 8;
  const __half* wbase = Wh + (size_t)R0 * HID + ks * 64;

  // rows 0..5 resident: 48 u32x4 = 192 VGPRs/thread, pinned against remat
  u32x4 wres[6][8];
#pragma unroll
  for (int r = 0; r < 6; ++r)
#pragma unroll
    for (int i = 0; i < 8; ++i)
      wres[r][i] = *(const u32x4*)(const void*)(wbase + (size_t)r * HID + i * 8);
#pragma unroll
  for (int r = 0; r < 6; ++r)
#pragma unroll
    for (int i = 0; i < 8; ++i)
      asm volatile("" : "+v"(wres[r][i]));

  // stage rows 6,7 into LDS, XOR-swizzled: logical chunk i at slot i^ks.
  // chunk(rb,j,ks) base = ((rb*2+j)*8+ks)*128; bx = base | ks*16;
  // element i at bx ^ (i*16). Row-7 chunk = row-6 chunk + 1024 bytes.
  const int off6 = (((rb * 2) * 8 + ks) << 7) | (ks << 4);
#pragma unroll
  for (int i = 0; i < 8; ++i) {
    u32x4 v6 = *(const u32x4*)(const void*)(wbase + (size_t)6 * HID + i * 8);
    u32x4 v7 = *(const u32x4*)(const void*)(wbase + (size_t)7 * HID + i * 8);
    *(u32x4*)(void*)(whl + (off6 ^ (i << 4)))        = v6;
    *(u32x4*)(void*)(whl + ((off6 ^ (i << 4)) + 1024)) = v7;
  }

  // h0 = 0 ; emit output block t=0
  const int hwb = (tid >> 6) * HCH + (tid & 63);  // my h slot (padded layout)
  hsh[hwb] = __float2half(0.f);
  io[(size_t)b * HID + tid] = 0.f;
  __syncthreads();

  const u32x4* hv = (const u32x4*)(const void*)(hsh + ks * HCH);
  float* iorow = io + (size_t)BATCH * HID + (size_t)b * HID + tid;
  float* pwr = part + ks * PST + R0;

  float xpv = *iorow;                    // xp_0

  for (int t = 0; t < T_STEPS; ++t) {
    // prefetch next step's xp — dots below hide the HBM latency
    float xpn = 0.f;
    if (t + 1 < T_STEPS) xpn = iorow[BATCH * HID];

    u32x4 hj[8];
#pragma unroll
    for (int i = 0; i < 8; ++i) hj[i] = hv[i];

    // rows 6,7 from LDS (issue early; resident dots below cover latency)
    float a6 = 0.f, a7 = 0.f;
#pragma unroll
    for (int i = 0; i < 8; ++i) {
      u32x4 w6 = *(const u32x4*)(const void*)(whl + (off6 ^ (i << 4)));
      u32x4 w7 = *(const u32x4*)(const void*)(whl + ((off6 ^ (i << 4)) + 1024));
      a6 = dot8v(w6, hj[i], a6);
      a7 = dot8v(w7, hj[i], a7);
    }

    float acc[6];
#pragma unroll
    for (int r = 0; r < 6; ++r) {
      float a = 0.f;
#pragma unroll
      for (int i = 0; i < 8; ++i) a = dot8v(wres[r][i], hj[i], a);
      acc[r] = a;
    }

    // partial sums -> LDS (two float4 stores, 16B-aligned)
    {
      float4 p0 = make_float4(acc[0], acc[1], acc[2], acc[3]);
      float4 p1 = make_float4(acc[4], acc[5], a6, a7);
      *(float4*)(void*)(pwr)     = p0;
      *(float4*)(void*)(pwr + 4) = p1;
    }
    __syncthreads();

    // thread tid == row n: reduce 8 k-slices, add xp, tanh, emit
    float s = 0.f;
#pragma unroll
    for (int k = 0; k < 8; ++k) s += part[k * PST + tid];
    s += xpv;                            // xp_t (prefetched)
    float e  = __expf(fminf(fmaxf(2.f * s, -40.f), 40.f));
    float hn = (e - 1.f) / (e + 1.f);
    *iorow = hn;                         // h_{t+1} overwrites xp_t in place
    hsh[hwb] = __float2half(hn);
    __syncthreads();

    xpv = xpn;
    iorow += BATCH * HID;
  }
}

extern "C" void kernel_launch(void* const* d_in, const int* in_sizes, int n_in,
                              void* d_out, int out_size, void* d_ws, size_t ws_size,
                              hipStream_t stream) {
  const float* x    = (const float*)d_in[0];   // (512,128,256) fp32
  const float* W    = (const float*)d_in[1];   // (512,768) fp32
  const float* bias = (const float*)d_in[2];   // (512,) fp32

  char* ws = (char*)d_ws;
  __half* Wx = (__half*)ws;                    // 512*256*2 = 256 KiB
  __half* Wh = (__half*)(ws + 262144);         // 512*512*2 = 512 KiB

  float* io = (float*)d_out;
  float* xp = io + (size_t)BATCH * HID;

  prep_w<<<1536, 256, 0, stream>>>(W, Wx, Wh);
  gemm_xp<<<4096, 256, 0, stream>>>(x, Wx, bias, xp);
  rnn_scan<<<BATCH, 512, 0, stream>>>(Wh, io);
}